// Round 1
// baseline (57.602 us; speedup 1.0000x reference)
//
#include <hip/hip_runtime.h>

#define BB 8
#define MM 2048
#define HH 1024
#define THRESH 0.99f
#define BMH ((size_t)BB * MM * HH)
#define BM (BB * MM)

// ---------------------------------------------------------------------------
// K1 / K3: per-batch-row prefix sum of a flag array.
// rank[b,m] = (inclusive cumsum of flags over m) - 1
// counts[b] = total flags in row b (optional, may be nullptr)
// One block per batch row; 256 threads; 8 elements/thread.
// ---------------------------------------------------------------------------
__global__ __launch_bounds__(256) void scan_kernel(const int* __restrict__ flags,
                                                   int* __restrict__ rank,
                                                   int* __restrict__ counts) {
    __shared__ int ssum[256];
    const int b = blockIdx.x;
    const int t = threadIdx.x;
    const int* row = flags + b * MM;

    int local[8];
    int s = 0;
#pragma unroll
    for (int i = 0; i < 8; ++i) {
        local[i] = (row[t * 8 + i] != 0) ? 1 : 0;
        s += local[i];
    }
    ssum[t] = s;
    __syncthreads();

    // Hillis-Steele inclusive scan over thread sums
    for (int off = 1; off < 256; off <<= 1) {
        int v = 0;
        if (t >= off) v = ssum[t - off];
        __syncthreads();
        if (t >= off) ssum[t] += v;
        __syncthreads();
    }

    int running = (t == 0) ? 0 : ssum[t - 1];  // exclusive prefix of this thread
    int* rrow = rank + b * MM;
#pragma unroll
    for (int i = 0; i < 8; ++i) {
        running += local[i];
        rrow[t * 8 + i] = running - 1;
    }
    if (t == 255 && counts != nullptr) counts[b] = ssum[255];
}

// ---------------------------------------------------------------------------
// K2: main per-token compute. One 64-lane wave per token; 4 waves/block.
//  - gather h row = x[b, rank[t], :] if run else 0
//  - p = sigmoid(h . p_w + p_b) * run
//  - masks, update, weighted_h_new, acc_p_new, remainders_new, run_new, exit_new
// ---------------------------------------------------------------------------
__global__ __launch_bounds__(256) void main_kernel(
    const float* __restrict__ x, const int* __restrict__ run,
    const float* __restrict__ acc_p, const float* __restrict__ weighted_h,
    const float* __restrict__ remainders, const int* __restrict__ exit_,
    const int* __restrict__ updates, const float* __restrict__ p_w,
    const float* __restrict__ p_b, const int* __restrict__ rank,
    float* __restrict__ out_wh, float* __restrict__ out_accp,
    float* __restrict__ out_rem, float* __restrict__ out_run,
    float* __restrict__ out_exit, int* __restrict__ run_new_i) {
    const int wave = threadIdx.x >> 6;
    const int lane = threadIdx.x & 63;
    const int t = blockIdx.x * 4 + wave;   // token in [0, B*M)
    const int b = t >> 11;                 // t / M

    const bool r = (run[t] != 0);
    const float* hrow = nullptr;
    float dot = 0.f;
    if (r) {
        const int src = rank[t];
        hrow = x + ((size_t)(b * MM + src)) * HH;
#pragma unroll
        for (int j = 0; j < 4; ++j) {
            const int idx = j * 256 + lane * 4;
            const float4 hv = *(const float4*)(hrow + idx);
            const float4 wv = *(const float4*)(p_w + idx);
            dot += hv.x * wv.x + hv.y * wv.y + hv.z * wv.z + hv.w * wv.w;
        }
    }
    // wave-wide sum (all lanes end with full sum)
#pragma unroll
    for (int off = 32; off > 0; off >>= 1) dot += __shfl_xor(dot, off, 64);

    const float p = r ? (1.f / (1.f + expf(-(dot + p_b[0])))) : 0.f;
    const float ap = acc_p[t];
    const bool mc = r && ((ap + p) < THRESH);
    const bool me = r && !mc;
    const float update = mc ? p : (me ? (1.f - ap) : 0.f);
    const float ap_new = mc ? (ap + p) : ap;

    const float* whrow = weighted_h + (size_t)t * HH;
    float* orow = out_wh + (size_t)t * HH;
#pragma unroll
    for (int j = 0; j < 4; ++j) {
        const int idx = j * 256 + lane * 4;
        const float4 wv = *(const float4*)(whrow + idx);
        float4 hv = make_float4(0.f, 0.f, 0.f, 0.f);
        if (r) hv = *(const float4*)(hrow + idx);
        float4 o;
        o.x = hv.x * update + wv.x;
        o.y = hv.y * update + wv.y;
        o.z = hv.z * update + wv.z;
        o.w = hv.w * update + wv.w;
        *(float4*)(orow + idx) = o;
    }

    if (lane == 0) {
        out_accp[t] = ap_new;
        out_rem[t] = remainders[t] + (me ? (1.f - ap_new) : 0.f);
        out_run[t] = mc ? 1.f : 0.f;
        out_exit[t] = (float)(exit_[t] + (me ? (updates[0] + 1) : 0));
        run_new_i[t] = mc ? 1 : 0;
    }
}

// ---------------------------------------------------------------------------
// K4: pack. For each token: if run_new, scatter its h row (= x[b, rank[t]])
// to packed slot rank2[t]; independently, slots m >= count get pad_h.
// One wave per token.
// ---------------------------------------------------------------------------
__global__ __launch_bounds__(256) void pack_kernel(
    const float* __restrict__ x, const float* __restrict__ pad_h,
    const int* __restrict__ rank, const int* __restrict__ run_new_i,
    const int* __restrict__ rank2, const int* __restrict__ counts,
    float* __restrict__ h_packed) {
    const int wave = threadIdx.x >> 6;
    const int lane = threadIdx.x & 63;
    const int t = blockIdx.x * 4 + wave;
    const int b = t >> 11;       // t / M
    const int m = t & (MM - 1);  // t % M
    const int cnt = counts[b];

    if (run_new_i[t] != 0) {
        const int dst = rank2[t];
        const float* src = x + ((size_t)(b * MM + rank[t])) * HH;
        float* out = h_packed + ((size_t)(b * MM + dst)) * HH;
#pragma unroll
        for (int j = 0; j < 4; ++j) {
            const int idx = j * 256 + lane * 4;
            *(float4*)(out + idx) = *(const float4*)(src + idx);
        }
    }
    if (m >= cnt) {
        float* out = h_packed + (size_t)t * HH;
#pragma unroll
        for (int j = 0; j < 4; ++j) {
            const int idx = j * 256 + lane * 4;
            *(float4*)(out + idx) = *(const float4*)(pad_h + idx);
        }
    }
}

extern "C" void kernel_launch(void* const* d_in, const int* in_sizes, int n_in,
                              void* d_out, int out_size, void* d_ws, size_t ws_size,
                              hipStream_t stream) {
    const float* x          = (const float*)d_in[0];
    const int*   run        = (const int*)d_in[1];
    const float* acc_p      = (const float*)d_in[2];
    const float* weighted_h = (const float*)d_in[3];
    const float* remainders = (const float*)d_in[4];
    const int*   exit_      = (const int*)d_in[5];
    const int*   updates    = (const int*)d_in[6];
    const float* pad_h      = (const float*)d_in[7];
    const float* p_w        = (const float*)d_in[8];
    const float* p_b        = (const float*)d_in[9];

    float* out = (float*)d_out;
    float* out_hpacked = out;                    // [B,M,H]
    float* out_wh      = out + BMH;              // [B,M,H]
    float* out_accp    = out + 2 * BMH;          // [B,M,1]
    float* out_rem     = out_accp + BM;          // [B,M,1]
    float* out_run     = out_rem + BM;           // [B,M]  (bool as 0/1 float)
    float* out_exit    = out_run + BM;           // [B,M,1] (int as float)

    int* rank      = (int*)d_ws;        // [B*M]
    int* run_new_i = rank + BM;         // [B*M]
    int* rank2     = run_new_i + BM;    // [B*M]
    int* counts    = rank2 + BM;        // [B]

    scan_kernel<<<BB, 256, 0, stream>>>(run, rank, nullptr);

    main_kernel<<<BM / 4, 256, 0, stream>>>(x, run, acc_p, weighted_h, remainders,
                                            exit_, updates, p_w, p_b, rank,
                                            out_wh, out_accp, out_rem, out_run,
                                            out_exit, run_new_i);

    scan_kernel<<<BB, 256, 0, stream>>>(run_new_i, rank2, counts);

    pack_kernel<<<BM / 4, 256, 0, stream>>>(x, pad_h, rank, run_new_i, rank2,
                                            counts, out_hpacked);
}